// Round 12
// baseline (2043.472 us; speedup 1.0000x reference)
//
#include <hip/hip_runtime.h>
#include <hip/hip_fp16.h>

#define N_NODES 20000
#define N_EDGES 320000
#define BATCH   64
#define N_IN    128
#define N_OUT   256
#define CAP     64
#define ITERS   150
#define LEAK    0.01f

#define CNT_MASK 0x3FFFFFFF
#define FLAG_BIT (1 << 30)

#define NSLICE 32          // batch pairs; slice s owns batch elems {2s,2s+1}
#define BPS    8           // blocks per slice (must all land on one XCD for L2 path)
#define NPB    2500        // nodes per block-chunk
#define NT     1024        // threads per block
#define NBLK   (NSLICE * BPS)
#define SLICE_U32 20480    // padded slice stride (u32) so refresh needs no guards
#define PAIRS  32          // edge-pair slots per node (CAP/2)
#define CTR_STRIDE 32      // 128 B between per-slice counters

typedef unsigned int uint;
typedef unsigned long long ull;
typedef _Float16 h2_t __attribute__((ext_vector_type(2)));

// MALL-coherent (always-correct, cross-XCD) accessors — relaxed only.
#define AT_LD32(p)   __hip_atomic_load((const uint*)(p), __ATOMIC_RELAXED, __HIP_MEMORY_SCOPE_AGENT)
#define AT_ST32(p,v) __hip_atomic_store((uint*)(p), (v), __ATOMIC_RELAXED, __HIP_MEMORY_SCOPE_AGENT)
#define AT_LD64(p)   __hip_atomic_load((const ull*)(p), __ATOMIC_RELAXED, __HIP_MEMORY_SCOPE_AGENT)
#define AT_LDI(p)    __hip_atomic_load((const int*)(p), __ATOMIC_RELAXED, __HIP_MEMORY_SCOPE_AGENT)
#define AT_ADDI(p,v) __hip_atomic_fetch_add((int*)(p), (v), __ATOMIC_RELAXED, __HIP_MEMORY_SCOPE_AGENT)

// L2-coherent load (bypass L1, served by this XCD's L2): inline-asm sc0 flag.
__device__ __forceinline__ int ld_sc0_i32(const int* p) {
    int v;
    asm volatile("global_load_dword %0, %1, off sc0\n\t"
                 "s_waitcnt vmcnt(0)"
                 : "=v"(v) : "v"(p) : "memory");
    return v;
}

__device__ __forceinline__ float fdot2u(uint w, uint h, float acc) {
    union { uint u; h2_t h; } a, b; a.u = w; b.u = h;
    return __builtin_amdgcn_fdot2(a.h, b.h, acc, false);
}

// ---------------------------------------------------------------------------
// setup: zero hGA (incl. padding), cnt, colpair/wpair, counters
// ---------------------------------------------------------------------------
__global__ void setup_kernel(uint* __restrict__ hGA, int* __restrict__ cnt,
                             uint* __restrict__ colpair, uint* __restrict__ wpair,
                             int* __restrict__ pre_ctr, int* __restrict__ mctr,
                             uint* __restrict__ xmask) {
    int idx = blockIdx.x * blockDim.x + threadIdx.x;
    int stride = gridDim.x * blockDim.x;
    for (int i = idx; i < NSLICE * SLICE_U32; i += stride) hGA[i] = 0u;
    for (int i = idx; i < N_NODES; i += stride) cnt[i] = 0;
    for (int i = idx; i < PAIRS * N_NODES; i += stride) { colpair[i] = 0u; wpair[i] = 0u; }
    for (int i = idx; i < NSLICE * CTR_STRIDE; i += stride) {
        pre_ctr[i] = 0; mctr[i] = 0; xmask[i] = 0u;
    }
}

// ---------------------------------------------------------------------------
// input scatter: bin[in_idx[i]][b] = bias + in_w[i]*x[b][i], last-wins.
// Flags the node (bit 30 of cnt).
// ---------------------------------------------------------------------------
__global__ void input_scatter_kernel(float* __restrict__ bin,
                                     const float* __restrict__ x,
                                     const float* __restrict__ in_w,
                                     const int* __restrict__ in_idx,
                                     const float* __restrict__ biases,
                                     int* __restrict__ cnt) {
    int i = blockIdx.x;
    int b = threadIdx.x;
    int node = in_idx[i];
    if (b == 0) atomicOr(&cnt[node], FLAG_BIT);
    for (int j = i + 1; j < N_IN; j++)
        if (in_idx[j] == node) return;
    bin[node * BATCH + b] = biases[node] + in_w[i] * x[b * N_IN + i];
}

// ---------------------------------------------------------------------------
// COO -> paired transposed ELL (node-major columns):
//   colpair[p][n] = col(2p) | col(2p+1)<<16 ; wpair[p][n] = half2(w0,w1)
// built with atomicOr into 16-bit subwords; zero slots = col0/w0 (harmless).
// ---------------------------------------------------------------------------
__global__ void ell_build_kernel(const int* __restrict__ rows,
                                 const int* __restrict__ cols,
                                 const float* __restrict__ rec_w,
                                 uint* __restrict__ colpair, uint* __restrict__ wpair,
                                 int* __restrict__ cnt) {
    int e = blockIdx.x * blockDim.x + threadIdx.x;
    if (e >= N_EDGES) return;
    int r = rows[e];
    int s = atomicAdd(&cnt[r], 1) & CNT_MASK;
    if (s < CAP) {
        int p = s >> 1, sh = (s & 1) * 16;
        atomicOr(&colpair[(size_t)p * N_NODES + r], (uint)cols[e] << sh);
        uint hw = (uint)__half_as_ushort(__float2half(rec_w[e]));
        atomicOr(&wpair[(size_t)p * N_NODES + r], hw << sh);
    }
}

// ---------------------------------------------------------------------------
// per-chunk descending counting sort by degree -> permG[rank] = node.
// Wave-uniform trip counts in the hot loop (kills ~1.8x padding waste).
// ---------------------------------------------------------------------------
__global__ __launch_bounds__(NT) void sort_kernel(const int* __restrict__ cnt,
                                                  int* __restrict__ permG) {
    __shared__ int hist[65], off[65];
    int chunk = blockIdx.x;
    int nbase = chunk * NPB;
    int tid = threadIdx.x;
    if (tid < 65) hist[tid] = 0;
    __syncthreads();
    for (int r = tid; r < NPB; r += NT) {
        int c = cnt[nbase + r] & CNT_MASK; if (c > CAP) c = CAP;
        atomicAdd(&hist[c], 1);
    }
    __syncthreads();
    if (tid == 0) {
        int run = 0;
        for (int c = CAP; c >= 0; c--) { off[c] = run; run += hist[c]; }
    }
    __syncthreads();
    for (int r = tid; r < NPB; r += NT) {
        int c = cnt[nbase + r] & CNT_MASK; if (c > CAP) c = CAP;
        int rk = atomicAdd(&off[c], 1);
        permG[nbase + rk] = nbase + r;
    }
}

// physically reorder meta by rank so hot-loop meta loads stay coalesced
__global__ void reorder_kernel(const uint* __restrict__ colpair,
                               const uint* __restrict__ wpair,
                               const int* __restrict__ permG,
                               uint* __restrict__ colR, uint* __restrict__ wR) {
    int r = blockIdx.x * blockDim.x + threadIdx.x;
    int p = blockIdx.y;
    if (r >= N_NODES) return;
    size_t o = (size_t)p * N_NODES;
    int n = permG[r];
    colR[o + r] = colpair[o + n];
    wR[o + r]   = wpair[o + n];
}

// ---------------------------------------------------------------------------
// shared pieces
// ---------------------------------------------------------------------------
__device__ __forceinline__ uint finish_node(float a0, float a1, float b0, float b1) {
    float r0 = b0 + a0, r1 = b1 + a1;
    float u0 = (r0 < 0.f) ? r0 * LEAK : r0;
    float u1 = (r1 < 0.f) ? r1 * LEAK : r1;
    float v0 = (u0 > 0.5f) ? (1.0f - 0.25f / u0) : u0;
    float v1 = (u1 > 0.5f) ? (1.0f - 0.25f / u1) : u1;
    union { __half2 h; uint u; } p;
    p.h = __halves2half2(__float2half(v0), __float2half(v1));
    return p.u;
}

__device__ __forceinline__ void hoist_consts(
        int nbase, int tid, int s,
        const int* __restrict__ cnt, const int* __restrict__ permG,
        const float* __restrict__ bin, const float* __restrict__ biases,
        int* rank, int* myn, float* mb0, float* mb1, bool* ma, int& kp) {
    int kmax = 0;
#pragma unroll
    for (int j = 0; j < 3; j++) {
        int sl = 3 * tid + j;
        ma[j] = (sl < NPB);
        rank[j] = nbase + (ma[j] ? sl : 0);
        int n = permG[rank[j]];
        myn[j] = n;
        int cv = cnt[n];
        int c = cv & CNT_MASK; if (c > CAP) c = CAP;
        if (ma[j] && c > kmax) kmax = c;
        if (cv & FLAG_BIT) {
            mb0[j] = bin[(size_t)n * BATCH + 2 * s];
            mb1[j] = bin[(size_t)n * BATCH + 2 * s + 1];
        } else {
            float bb = biases[n]; mb0[j] = bb; mb1[j] = bb;
        }
    }
    kp = (kmax + 1) >> 1;
}

// 3 node streams x paired edges: 6 independent ds_reads per iteration,
// fdot2 fp32 accumulate; zero pair slots contribute exactly 0.
__device__ __forceinline__ void compute_pairs(
        const int* rank, int kp,
        const uint* __restrict__ colR, const uint* __restrict__ wR,
        const uint* __restrict__ lds_h, float* a0, float* a1) {
    a0[0] = a0[1] = a0[2] = 0.f;
    a1[0] = a1[1] = a1[2] = 0.f;
#pragma unroll 2
    for (int p = 0; p < kp; p++) {
        size_t o = (size_t)p * N_NODES;
#pragma unroll
        for (int j = 0; j < 3; j++) {
            uint cc = colR[o + rank[j]];
            uint ww = wR[o + rank[j]];
            uint ha = lds_h[cc & 0xFFFFu];
            uint hb = lds_h[cc >> 16];
            uint lo = __builtin_amdgcn_perm(hb, ha, 0x05040100u);
            uint hi = __builtin_amdgcn_perm(hb, ha, 0x07060302u);
            a0[j] = fdot2u(ww, lo, a0[j]);
            a1[j] = fdot2u(ww, hi, a1[j]);
        }
    }
}

// ---------------------------------------------------------------------------
// persistent kernel. Pre-phase verifies (via HW_REG_XCC_ID + MALL atomics)
// that the slice's 8 blocks share an XCD; if so, exchange runs entirely in
// that XCD's L2 (plain stores + sc0 loads + wg-scope atomic barrier), else
// falls back to the proven MALL path (round 11). No fences, no L2 inv ever.
// ---------------------------------------------------------------------------
__global__ __launch_bounds__(NT) void persistent_kernel(
        uint* hGA, uint* hGB,
        const float* __restrict__ bin, const float* __restrict__ biases,
        const uint* __restrict__ colR, const uint* __restrict__ wR,
        const int* __restrict__ cnt, const int* __restrict__ permG,
        int* pre_ctr, int* mctr, uint* xmask) {
    extern __shared__ uint lds_h[];          // 80 KB slice mirror
    int bid = blockIdx.x, tid = threadIdx.x;
    int s = bid >> 3, sub = bid & 7;
    int nbase = sub * NPB;

    // ---- pre-phase: XCD homogeneity check (always MALL-correct) ----
    if (tid == 0) {
        uint xcd = (uint)__builtin_amdgcn_s_getreg(63508) & 31u;  // HW_REG_XCC_ID
        __hip_atomic_fetch_or(&xmask[s * CTR_STRIDE], 1u << xcd,
                              __ATOMIC_RELAXED, __HIP_MEMORY_SCOPE_AGENT);
        AT_ADDI(&pre_ctr[s * CTR_STRIDE], 1);
        while (AT_LDI(&pre_ctr[s * CTR_STRIDE]) < BPS) __builtin_amdgcn_s_sleep(2);
        uint m = AT_LD32(&xmask[s * CTR_STRIDE]);
        lds_h[0] = (__popc(m) == 1) ? 1u : 0u;
    }
    __syncthreads();
    const bool l2p = (lds_h[0] != 0u);
    __syncthreads();

    int rank[3], myn[3]; float mb0[3], mb1[3]; bool ma[3]; int kp;
    hoist_consts(nbase, tid, s, cnt, permG, bin, biases, rank, myn, mb0, mb1, ma, kp);

    for (int i = tid; i < N_NODES; i += NT) lds_h[i] = 0u;   // h_{-1} = 0
    __syncthreads();

    uint* hA_s = hGA + (size_t)s * SLICE_U32;
    uint* hB_s = hGB + (size_t)s * SLICE_U32;
    int* mc = &mctr[s * CTR_STRIDE];

    for (int t = 0; t < ITERS; t++) {
        uint* hout = (t & 1) ? hB_s : hA_s;
        float a0[3], a1[3];
        compute_pairs(rank, kp, colR, wR, lds_h, a0, a1);
        uint v[3];
#pragma unroll
        for (int j = 0; j < 3; j++) v[j] = finish_node(a0[j], a1[j], mb0[j], mb1[j]);
        if (l2p) {
#pragma unroll
            for (int j = 0; j < 3; j++) if (ma[j]) hout[myn[j]] = v[j];
        } else {
#pragma unroll
            for (int j = 0; j < 3; j++) if (ma[j]) AT_ST32(&hout[myn[j]], v[j]);
        }
        if (t == ITERS - 1) break;

        __syncthreads();                       // drains publish stores to L2/MALL
        if (tid == 0) {
            int target = BPS * (t + 1);
            if (l2p) {
                __hip_atomic_fetch_add(mc, 1, __ATOMIC_RELAXED, __HIP_MEMORY_SCOPE_WORKGROUP);
                while (ld_sc0_i32(mc) < target) __builtin_amdgcn_s_sleep(2);
            } else {
                AT_ADDI(mc, 1);
                while (AT_LDI(mc) < target) __builtin_amdgcn_s_sleep(2);
            }
        }
        __syncthreads();

        // refresh the LDS mirror from the freshly published buffer
        if (l2p) {
            const ull* src = (const ull*)hout;           // padded to 10240 u64
            ull* dst = (ull*)lds_h;
#pragma unroll
            for (int g = 0; g < 2; g++) {
                int i0 = tid + g * 5 * NT;
                const ull *p0 = src + i0, *p1 = src + i0 + NT, *p2 = src + i0 + 2 * NT,
                          *p3 = src + i0 + 3 * NT, *p4 = src + i0 + 4 * NT;
                ull v0, v1, v2, v3, v4;
                asm volatile(
                    "global_load_dwordx2 %0, %5, off sc0\n\t"
                    "global_load_dwordx2 %1, %6, off sc0\n\t"
                    "global_load_dwordx2 %2, %7, off sc0\n\t"
                    "global_load_dwordx2 %3, %8, off sc0\n\t"
                    "global_load_dwordx2 %4, %9, off sc0\n\t"
                    "s_waitcnt vmcnt(0)"
                    : "=&v"(v0), "=&v"(v1), "=&v"(v2), "=&v"(v3), "=&v"(v4)
                    : "v"(p0), "v"(p1), "v"(p2), "v"(p3), "v"(p4)
                    : "memory");
                if (i0            < N_NODES / 2) dst[i0]          = v0;
                if (i0 + NT       < N_NODES / 2) dst[i0 + NT]     = v1;
                if (i0 + 2 * NT   < N_NODES / 2) dst[i0 + 2 * NT] = v2;
                if (i0 + 3 * NT   < N_NODES / 2) dst[i0 + 3 * NT] = v3;
                if (i0 + 4 * NT   < N_NODES / 2) dst[i0 + 4 * NT] = v4;
            }
        } else {
            const ull* src = (const ull*)hout;
            ull* dst = (ull*)lds_h;
            for (int i = tid; i < N_NODES / 2; i += NT) dst[i] = AT_LD64(&src[i]);
        }
        __syncthreads();
    }
}

// ---------------------------------------------------------------------------
// fallback: one step per launch (dispatch boundary = sync), same numerics
// ---------------------------------------------------------------------------
__global__ __launch_bounds__(NT) void step_kernel(
        const uint* __restrict__ hprev, uint* __restrict__ hnext,
        const float* __restrict__ bin, const float* __restrict__ biases,
        const uint* __restrict__ colR, const uint* __restrict__ wR,
        const int* __restrict__ cnt, const int* __restrict__ permG) {
    extern __shared__ uint lds_h[];
    int bid = blockIdx.x, tid = threadIdx.x;
    int s = bid >> 3, sub = bid & 7;
    int nbase = sub * NPB;

    int rank[3], myn[3]; float mb0[3], mb1[3]; bool ma[3]; int kp;
    hoist_consts(nbase, tid, s, cnt, permG, bin, biases, rank, myn, mb0, mb1, ma, kp);

    const uint* hp = hprev + (size_t)s * SLICE_U32;
    for (int i = tid; i < N_NODES; i += NT) lds_h[i] = hp[i];
    __syncthreads();

    float a0[3], a1[3];
    compute_pairs(rank, kp, colR, wR, lds_h, a0, a1);
    uint* ho = hnext + (size_t)s * SLICE_U32;
#pragma unroll
    for (int j = 0; j < 3; j++)
        if (ma[j]) ho[myn[j]] = finish_node(a0[j], a1[j], mb0[j], mb1[j]);
}

// ---------------------------------------------------------------------------
// output gather: out[b][o] = out_w[o] * h[out_idx[o]][b]
// ---------------------------------------------------------------------------
__global__ void output_kernel(const uint* __restrict__ hfinal,
                              const int* __restrict__ out_idx,
                              const float* __restrict__ out_w,
                              float* __restrict__ out) {
    int o = threadIdx.x;
    int b = blockIdx.x;
    uint v = hfinal[(size_t)(b >> 1) * SLICE_U32 + out_idx[o]];
    unsigned short h = (b & 1) ? (unsigned short)(v >> 16) : (unsigned short)(v & 0xFFFF);
    out[b * N_OUT + o] = out_w[o] * __half2float(__ushort_as_half(h));
}

// ---------------------------------------------------------------------------
extern "C" void kernel_launch(void* const* d_in, const int* in_sizes, int n_in,
                              void* d_out, int out_size, void* d_ws, size_t ws_size,
                              hipStream_t stream) {
    const float* x      = (const float*)d_in[0];
    const float* in_w   = (const float*)d_in[1];
    const float* out_w  = (const float*)d_in[2];
    const float* rec_w  = (const float*)d_in[3];
    const float* biases = (const float*)d_in[4];
    const int*   rows   = (const int*)d_in[5];
    const int*   cols   = (const int*)d_in[6];
    const int*   in_idx = (const int*)d_in[7];
    const int*   oidx   = (const int*)d_in[8];
    float* out = (float*)d_out;

    char* ws = (char*)d_ws;
    uint*  hGA     = (uint*)ws; ws += (size_t)NSLICE * SLICE_U32 * 4;  // 2.62 MB
    uint*  hGB     = (uint*)ws; ws += (size_t)NSLICE * SLICE_U32 * 4;  // 2.62 MB
    float* bin     = (float*)ws; ws += (size_t)N_NODES * BATCH * 4;    // 5.12 MB
    uint*  colpair = (uint*)ws;  ws += (size_t)PAIRS * N_NODES * 4;    // 2.56 MB
    uint*  wpair   = (uint*)ws;  ws += (size_t)PAIRS * N_NODES * 4;    // 2.56 MB
    uint*  colR    = (uint*)ws;  ws += (size_t)PAIRS * N_NODES * 4;    // 2.56 MB
    uint*  wR      = (uint*)ws;  ws += (size_t)PAIRS * N_NODES * 4;    // 2.56 MB
    int*   cnt     = (int*)ws;   ws += (size_t)N_NODES * 4;            // 80 KB
    int*   permG   = (int*)ws;   ws += (size_t)N_NODES * 4;            // 80 KB
    int*   pre_ctr = (int*)ws;   ws += (size_t)NSLICE * CTR_STRIDE * 4;
    int*   mctr    = (int*)ws;   ws += (size_t)NSLICE * CTR_STRIDE * 4;
    uint*  xmask   = (uint*)ws;  ws += (size_t)NSLICE * CTR_STRIDE * 4;

    const int shmem = N_NODES * 4;   // 80 KB dynamic LDS
    hipFuncSetAttribute((const void*)persistent_kernel,
                        hipFuncAttributeMaxDynamicSharedMemorySize, shmem);
    hipFuncSetAttribute((const void*)step_kernel,
                        hipFuncAttributeMaxDynamicSharedMemorySize, shmem);

    setup_kernel<<<2048, 256, 0, stream>>>(hGA, cnt, colpair, wpair,
                                           pre_ctr, mctr, xmask);
    input_scatter_kernel<<<N_IN, BATCH, 0, stream>>>(bin, x, in_w, in_idx,
                                                     biases, cnt);
    ell_build_kernel<<<(N_EDGES + 255) / 256, 256, 0, stream>>>(rows, cols, rec_w,
                                                                colpair, wpair, cnt);
    sort_kernel<<<BPS, NT, 0, stream>>>(cnt, permG);
    reorder_kernel<<<dim3((N_NODES + 255) / 256, PAIRS), 256, 0, stream>>>(
        colpair, wpair, permG, colR, wR);

    void* args[] = { (void*)&hGA, (void*)&hGB, (void*)&bin, (void*)&biases,
                     (void*)&colR, (void*)&wR, (void*)&cnt, (void*)&permG,
                     (void*)&pre_ctr, (void*)&mctr, (void*)&xmask };
    hipError_t ce = hipLaunchCooperativeKernel((void*)persistent_kernel,
                                               dim3(NBLK), dim3(NT),
                                               args, shmem, stream);
    const uint* hfinal;
    if (ce == hipSuccess) {
        hfinal = hGB;                 // t=149 (odd) wrote hGB
    } else {
        uint* pa = hGA;
        uint* pb = hGB;
        for (int t = 0; t < ITERS; t++) {
            step_kernel<<<NBLK, NT, shmem, stream>>>(pa, pb, bin, biases,
                                                     colR, wR, cnt, permG);
            uint* tmp = pa; pa = pb; pb = tmp;
        }
        hfinal = pa;                  // last write landed in the buffer now in pa
    }

    output_kernel<<<BATCH, N_OUT, 0, stream>>>(hfinal, oidx, out_w, out);
}

// Round 14
// 1673.172 us; speedup vs baseline: 1.2213x; 1.2213x over previous
//
#include <hip/hip_runtime.h>
#include <hip/hip_fp16.h>

#define N_NODES 20000
#define N_EDGES 320000
#define BATCH   64
#define N_IN    128
#define N_OUT   256
#define CAP     64
#define ITERS   150
#define LEAK    0.01f

#define CNT_MASK 0x3FFFFFFF
#define FLAG_BIT (1 << 30)

#define NSLICE 32          // batch pairs; slice s owns batch elems {2s,2s+1}
#define BPS    8           // blocks per slice
#define NPB    2500        // ranks per block-chunk
#define NT     1024        // threads per block
#define NBLK   (NSLICE * BPS)
#define SLICE_U32 20480    // padded slice stride (u32)
#define SLICE_U64 (SLICE_U32 / 2)
#define PAIRS  32          // edge-pair slots per node (CAP/2)
#define CTR_STRIDE 32      // 128 B between per-slice counters

typedef unsigned int uint;
typedef unsigned long long ull;
typedef _Float16 h2_t __attribute__((ext_vector_type(2)));

// MALL-coherent accessors — RELAXED ONLY, single uniform protocol everywhere.
// (acquire/release = whole-L2 inv/wb on gfx950: round-8/10 disease. Mixed
// protocols selected at runtime: round-13 hang. Neither ever again.)
#define AT_LD32(p)   __hip_atomic_load((const uint*)(p), __ATOMIC_RELAXED, __HIP_MEMORY_SCOPE_AGENT)
#define AT_ST32(p,v) __hip_atomic_store((uint*)(p), (v), __ATOMIC_RELAXED, __HIP_MEMORY_SCOPE_AGENT)
#define AT_LD64(p)   __hip_atomic_load((const ull*)(p), __ATOMIC_RELAXED, __HIP_MEMORY_SCOPE_AGENT)
#define AT_ST64(p,v) __hip_atomic_store((ull*)(p), (v), __ATOMIC_RELAXED, __HIP_MEMORY_SCOPE_AGENT)
#define AT_LDI(p)    __hip_atomic_load((const int*)(p), __ATOMIC_RELAXED, __HIP_MEMORY_SCOPE_AGENT)
#define AT_ADDI(p,v) __hip_atomic_fetch_add((int*)(p), (v), __ATOMIC_RELAXED, __HIP_MEMORY_SCOPE_AGENT)

__device__ __forceinline__ float fdot2u(uint w, uint h, float acc) {
    union { uint u; h2_t h; } a, b; a.u = w; b.u = h;
    return __builtin_amdgcn_fdot2(a.h, b.h, acc, false);
}

// ---------------------------------------------------------------------------
// setup: zero both h buffers (incl. padding), cnt, meta, counters
// ---------------------------------------------------------------------------
__global__ void setup_kernel(uint* __restrict__ hGA, uint* __restrict__ hGB,
                             int* __restrict__ cnt,
                             uint* __restrict__ colpair, uint* __restrict__ wpair,
                             int* __restrict__ mctr) {
    int idx = blockIdx.x * blockDim.x + threadIdx.x;
    int stride = gridDim.x * blockDim.x;
    for (int i = idx; i < NSLICE * SLICE_U32; i += stride) { hGA[i] = 0u; hGB[i] = 0u; }
    for (int i = idx; i < N_NODES; i += stride) cnt[i] = 0;
    for (int i = idx; i < PAIRS * N_NODES; i += stride) { colpair[i] = 0u; wpair[i] = 0u; }
    for (int i = idx; i < NSLICE * CTR_STRIDE; i += stride) mctr[i] = 0;
}

// ---------------------------------------------------------------------------
// input scatter: bin[in_idx[i]][b] = bias + in_w[i]*x[b][i], last-wins.
// Flags the node (bit 30 of cnt).
// ---------------------------------------------------------------------------
__global__ void input_scatter_kernel(float* __restrict__ bin,
                                     const float* __restrict__ x,
                                     const float* __restrict__ in_w,
                                     const int* __restrict__ in_idx,
                                     const float* __restrict__ biases,
                                     int* __restrict__ cnt) {
    int i = blockIdx.x;
    int b = threadIdx.x;
    int node = in_idx[i];
    if (b == 0) atomicOr(&cnt[node], FLAG_BIT);
    for (int j = i + 1; j < N_IN; j++)
        if (in_idx[j] == node) return;
    bin[node * BATCH + b] = biases[node] + in_w[i] * x[b * N_IN + i];
}

// ---------------------------------------------------------------------------
// COO -> paired transposed ELL in NODE space (atomicOr into 16-bit subwords)
// ---------------------------------------------------------------------------
__global__ void ell_build_kernel(const int* __restrict__ rows,
                                 const int* __restrict__ cols,
                                 const float* __restrict__ rec_w,
                                 uint* __restrict__ colpair, uint* __restrict__ wpair,
                                 int* __restrict__ cnt) {
    int e = blockIdx.x * blockDim.x + threadIdx.x;
    if (e >= N_EDGES) return;
    int r = rows[e];
    int s = atomicAdd(&cnt[r], 1) & CNT_MASK;
    if (s < CAP) {
        int p = s >> 1, sh = (s & 1) * 16;
        atomicOr(&colpair[(size_t)p * N_NODES + r], (uint)cols[e] << sh);
        uint hw = (uint)__half_as_ushort(__float2half(rec_w[e]));
        atomicOr(&wpair[(size_t)p * N_NODES + r], hw << sh);
    }
}

// ---------------------------------------------------------------------------
// per-chunk descending counting sort by degree.
// permG[rank] = node, rankOf[node] = rank (chunk-local ranges preserved).
// ---------------------------------------------------------------------------
__global__ __launch_bounds__(NT) void sort_kernel(const int* __restrict__ cnt,
                                                  int* __restrict__ permG,
                                                  int* __restrict__ rankOf) {
    __shared__ int hist[65], off[65];
    int nbase = blockIdx.x * NPB;
    int tid = threadIdx.x;
    if (tid < 65) hist[tid] = 0;
    __syncthreads();
    for (int r = tid; r < NPB; r += NT) {
        int c = cnt[nbase + r] & CNT_MASK; if (c > CAP) c = CAP;
        atomicAdd(&hist[c], 1);
    }
    __syncthreads();
    if (tid == 0) {
        int run = 0;
        for (int c = CAP; c >= 0; c--) { off[c] = run; run += hist[c]; }
    }
    __syncthreads();
    for (int r = tid; r < NPB; r += NT) {
        int c = cnt[nbase + r] & CNT_MASK; if (c > CAP) c = CAP;
        int rk = atomicAdd(&off[c], 1);
        permG[nbase + rk] = nbase + r;
        rankOf[nbase + r] = nbase + rk;
    }
}

// reorder meta into RANK space and remap columns into RANK space
__global__ void reorder_kernel(const uint* __restrict__ colpair,
                               const uint* __restrict__ wpair,
                               const int* __restrict__ permG,
                               const int* __restrict__ rankOf,
                               uint* __restrict__ colR, uint* __restrict__ wR) {
    int r = blockIdx.x * blockDim.x + threadIdx.x;
    int p = blockIdx.y;
    if (r >= N_NODES) return;
    size_t o = (size_t)p * N_NODES;
    int n = permG[r];
    uint cc = colpair[o + n];
    uint lo = (uint)rankOf[cc & 0xFFFFu];
    uint hi = (uint)rankOf[cc >> 16];
    colR[o + r] = lo | (hi << 16);
    wR[o + r]   = wpair[o + n];
}

// ---------------------------------------------------------------------------
// shared pieces
// ---------------------------------------------------------------------------
__device__ __forceinline__ uint finish_node(float a0, float a1, float b0, float b1) {
    float r0 = b0 + a0, r1 = b1 + a1;
    float u0 = (r0 < 0.f) ? r0 * LEAK : r0;
    float u1 = (r1 < 0.f) ? r1 * LEAK : r1;
    float v0 = (u0 > 0.5f) ? (1.0f - 0.25f / u0) : u0;
    float v1 = (u1 > 0.5f) ? (1.0f - 0.25f / u1) : u1;
    union { __half2 h; uint u; } p;
    p.h = __halves2half2(__float2half(v0), __float2half(v1));
    return p.u;
}

// thread owns 3 ADJACENT ranks (3*tid..3*tid+2): sorted -> near-uniform trip.
__device__ __forceinline__ void hoist_consts(
        int nbase, int tid, int s,
        const int* __restrict__ cnt, const int* __restrict__ permG,
        const float* __restrict__ bin, const float* __restrict__ biases,
        int* rank, float* mb0, float* mb1, bool* ma, int& kp) {
    int kmax = 0;
#pragma unroll
    for (int j = 0; j < 3; j++) {
        int sl = 3 * tid + j;
        ma[j] = (sl < NPB);
        rank[j] = nbase + (ma[j] ? sl : 0);
        int n = permG[rank[j]];
        int cv = cnt[n];
        int c = cv & CNT_MASK; if (c > CAP) c = CAP;
        if (ma[j] && c > kmax) kmax = c;
        if (cv & FLAG_BIT) {
            mb0[j] = bin[(size_t)n * BATCH + 2 * s];
            mb1[j] = bin[(size_t)n * BATCH + 2 * s + 1];
        } else {
            float bb = biases[n]; mb0[j] = bb; mb1[j] = bb;
        }
    }
    kp = (kmax + 1) >> 1;
}

// 3 rank streams x paired edges: 6 independent ds_reads/iter, fdot2 accum.
__device__ __forceinline__ void compute_pairs(
        const int* rank, int kp,
        const uint* __restrict__ colR, const uint* __restrict__ wR,
        const uint* __restrict__ lds_h, float* a0, float* a1) {
    a0[0] = a0[1] = a0[2] = 0.f;
    a1[0] = a1[1] = a1[2] = 0.f;
#pragma unroll 2
    for (int p = 0; p < kp; p++) {
        size_t o = (size_t)p * N_NODES;
#pragma unroll
        for (int j = 0; j < 3; j++) {
            uint cc = colR[o + rank[j]];
            uint ww = wR[o + rank[j]];
            uint ha = lds_h[cc & 0xFFFFu];
            uint hb = lds_h[cc >> 16];
            uint lo = __builtin_amdgcn_perm(hb, ha, 0x05040100u);
            uint hi = __builtin_amdgcn_perm(hb, ha, 0x07060302u);
            a0[j] = fdot2u(ww, lo, a0[j]);
            a1[j] = fdot2u(ww, hi, a1[j]);
        }
    }
}

// ---------------------------------------------------------------------------
// persistent kernel: round-11's proven MALL skeleton + rank-space state.
// Per step: compute (LDS) -> ds_write own -> publish own range as coalesced
// u64 agent stores (staged through LDS) -> counter barrier -> refresh
// non-own range. One protocol, no fences, no runtime selection.
// ---------------------------------------------------------------------------
__global__ __launch_bounds__(NT) void persistent_kernel(
        uint* hGA, uint* hGB,
        const float* __restrict__ bin, const float* __restrict__ biases,
        const uint* __restrict__ colR, const uint* __restrict__ wR,
        const int* __restrict__ cnt, const int* __restrict__ permG,
        int* mctr) {
    extern __shared__ uint lds_h[];          // SLICE_U32 u32 = 80 KB mirror
    int bid = blockIdx.x, tid = threadIdx.x;
    int s = bid >> 3, sub = bid & 7;
    int nbase = sub * NPB;

    int rank[3]; float mb0[3], mb1[3]; bool ma[3]; int kp;
    hoist_consts(nbase, tid, s, cnt, permG, bin, biases, rank, mb0, mb1, ma, kp);

    for (int i = tid; i < SLICE_U32; i += NT) lds_h[i] = 0u;   // h_{-1} = 0
    __syncthreads();

    uint* hA_s = hGA + (size_t)s * SLICE_U32;
    uint* hB_s = hGB + (size_t)s * SLICE_U32;
    int* mc = &mctr[s * CTR_STRIDE];
    const int lo64 = sub * (NPB / 2), hi64 = lo64 + NPB / 2;   // own u64 range

    for (int t = 0; t < ITERS; t++) {
        uint* hout = (t & 1) ? hB_s : hA_s;

        float a0[3], a1[3];
        compute_pairs(rank, kp, colR, wR, lds_h, a0, a1);
        uint v[3];
#pragma unroll
        for (int j = 0; j < 3; j++) v[j] = finish_node(a0[j], a1[j], mb0[j], mb1[j]);

        __syncthreads();                     // all LDS reads of step t done
#pragma unroll
        for (int j = 0; j < 3; j++)
            if (ma[j]) lds_h[rank[j]] = v[j];
        __syncthreads();                     // own LDS range fresh

        // publish own range: stride-1 u64 agent stores (fully coalesced)
        {
            const ull* lsrc = (const ull*)lds_h;
            ull* gdst = (ull*)hout;
            for (int i = lo64 + tid; i < hi64; i += NT)
                AT_ST64(&gdst[i], lsrc[i]);
        }
        if (t == ITERS - 1) break;

        __syncthreads();                     // publish drained (vmcnt0 @ barrier)
        if (tid == 0) {
            AT_ADDI(mc, 1);
            int target = BPS * (t + 1);
            while (AT_LDI(mc) < target) __builtin_amdgcn_s_sleep(2);
        }
        __syncthreads();

        // refresh non-own ranks from the MALL double buffer (u64 coalesced)
        {
            const ull* src = (const ull*)hout;
            ull* dst = (ull*)lds_h;
            for (int i = tid; i < SLICE_U64; i += NT)
                if (i < lo64 || i >= hi64) dst[i] = AT_LD64(&src[i]);
        }
        __syncthreads();
    }
}

// ---------------------------------------------------------------------------
// fallback: one step per launch (dispatch boundary = sync), same numerics
// ---------------------------------------------------------------------------
__global__ __launch_bounds__(NT) void step_kernel(
        const uint* __restrict__ hprev, uint* __restrict__ hnext,
        const float* __restrict__ bin, const float* __restrict__ biases,
        const uint* __restrict__ colR, const uint* __restrict__ wR,
        const int* __restrict__ cnt, const int* __restrict__ permG) {
    extern __shared__ uint lds_h[];
    int bid = blockIdx.x, tid = threadIdx.x;
    int s = bid >> 3, sub = bid & 7;
    int nbase = sub * NPB;

    int rank[3]; float mb0[3], mb1[3]; bool ma[3]; int kp;
    hoist_consts(nbase, tid, s, cnt, permG, bin, biases, rank, mb0, mb1, ma, kp);

    const uint* hp = hprev + (size_t)s * SLICE_U32;
    for (int i = tid; i < SLICE_U32; i += NT) lds_h[i] = hp[i];
    __syncthreads();

    float a0[3], a1[3];
    compute_pairs(rank, kp, colR, wR, lds_h, a0, a1);
    uint* ho = hnext + (size_t)s * SLICE_U32;
#pragma unroll
    for (int j = 0; j < 3; j++)
        if (ma[j]) ho[rank[j]] = finish_node(a0[j], a1[j], mb0[j], mb1[j]);
}

// ---------------------------------------------------------------------------
// output gather: out[b][o] = out_w[o] * h[rankOf[out_idx[o]]][b]
// ---------------------------------------------------------------------------
__global__ void output_kernel(const uint* __restrict__ hfinal,
                              const int* __restrict__ out_idx,
                              const int* __restrict__ rankOf,
                              const float* __restrict__ out_w,
                              float* __restrict__ out) {
    int o = threadIdx.x;
    int b = blockIdx.x;
    uint v = hfinal[(size_t)(b >> 1) * SLICE_U32 + rankOf[out_idx[o]]];
    unsigned short h = (b & 1) ? (unsigned short)(v >> 16) : (unsigned short)(v & 0xFFFF);
    out[b * N_OUT + o] = out_w[o] * __half2float(__ushort_as_half(h));
}

// ---------------------------------------------------------------------------
extern "C" void kernel_launch(void* const* d_in, const int* in_sizes, int n_in,
                              void* d_out, int out_size, void* d_ws, size_t ws_size,
                              hipStream_t stream) {
    const float* x      = (const float*)d_in[0];
    const float* in_w   = (const float*)d_in[1];
    const float* out_w  = (const float*)d_in[2];
    const float* rec_w  = (const float*)d_in[3];
    const float* biases = (const float*)d_in[4];
    const int*   rows   = (const int*)d_in[5];
    const int*   cols   = (const int*)d_in[6];
    const int*   in_idx = (const int*)d_in[7];
    const int*   oidx   = (const int*)d_in[8];
    float* out = (float*)d_out;

    char* ws = (char*)d_ws;
    uint*  hGA     = (uint*)ws;  ws += (size_t)NSLICE * SLICE_U32 * 4;  // 2.62 MB
    uint*  hGB     = (uint*)ws;  ws += (size_t)NSLICE * SLICE_U32 * 4;  // 2.62 MB
    float* bin     = (float*)ws; ws += (size_t)N_NODES * BATCH * 4;     // 5.12 MB
    uint*  colpair = (uint*)ws;  ws += (size_t)PAIRS * N_NODES * 4;     // 2.56 MB
    uint*  wpair   = (uint*)ws;  ws += (size_t)PAIRS * N_NODES * 4;     // 2.56 MB
    uint*  colR    = (uint*)ws;  ws += (size_t)PAIRS * N_NODES * 4;     // 2.56 MB
    uint*  wR      = (uint*)ws;  ws += (size_t)PAIRS * N_NODES * 4;     // 2.56 MB
    int*   cnt     = (int*)ws;   ws += (size_t)N_NODES * 4;             // 80 KB
    int*   permG   = (int*)ws;   ws += (size_t)N_NODES * 4;             // 80 KB
    int*   rankOf  = (int*)ws;   ws += (size_t)N_NODES * 4;             // 80 KB
    int*   mctr    = (int*)ws;   ws += (size_t)NSLICE * CTR_STRIDE * 4;

    const int shmem = SLICE_U32 * 4;   // 81920 B dynamic LDS
    hipFuncSetAttribute((const void*)persistent_kernel,
                        hipFuncAttributeMaxDynamicSharedMemorySize, shmem);
    hipFuncSetAttribute((const void*)step_kernel,
                        hipFuncAttributeMaxDynamicSharedMemorySize, shmem);

    setup_kernel<<<2048, 256, 0, stream>>>(hGA, hGB, cnt, colpair, wpair, mctr);
    input_scatter_kernel<<<N_IN, BATCH, 0, stream>>>(bin, x, in_w, in_idx,
                                                     biases, cnt);
    ell_build_kernel<<<(N_EDGES + 255) / 256, 256, 0, stream>>>(rows, cols, rec_w,
                                                                colpair, wpair, cnt);
    sort_kernel<<<N_NODES / NPB, NT, 0, stream>>>(cnt, permG, rankOf);
    reorder_kernel<<<dim3((N_NODES + 255) / 256, PAIRS), 256, 0, stream>>>(
        colpair, wpair, permG, rankOf, colR, wR);

    void* args[] = { (void*)&hGA, (void*)&hGB, (void*)&bin, (void*)&biases,
                     (void*)&colR, (void*)&wR, (void*)&cnt, (void*)&permG,
                     (void*)&mctr };
    hipError_t ce = hipLaunchCooperativeKernel((void*)persistent_kernel,
                                               dim3(NBLK), dim3(NT),
                                               args, shmem, stream);
    const uint* hfinal;
    if (ce == hipSuccess) {
        hfinal = hGB;                 // t=149 (odd) wrote hGB
    } else {
        uint* pa = hGA;
        uint* pb = hGB;
        for (int t = 0; t < ITERS; t++) {
            step_kernel<<<NBLK, NT, shmem, stream>>>(pa, pb, bin, biases,
                                                     colR, wR, cnt, permG);
            uint* tmp = pa; pa = pb; pb = tmp;
        }
        hfinal = pa;                  // last write landed in the buffer now in pa
    }

    output_kernel<<<BATCH, N_OUT, 0, stream>>>(hfinal, oidx, rankOf, out_w, out);
}

// Round 15
// 1088.817 us; speedup vs baseline: 1.8768x; 1.5367x over previous
//
#include <hip/hip_runtime.h>
#include <hip/hip_fp16.h>

#define N_NODES 20000
#define N_EDGES 320000
#define BATCH   64
#define N_IN    128
#define N_OUT   256
#define CAP     64
#define ITERS   150
#define LEAK    0.01f

#define CNT_MASK 0x3FFFFFFF
#define FLAG_BIT (1 << 30)

#define NSLICE 32          // batch pairs; slice s owns batch elems {2s,2s+1}
#define BPS    8           // blocks per slice
#define NPB    2500        // ranks per block-chunk
#define NT     1024        // threads per block
#define NBLK   (NSLICE * BPS)
#define SLICE_U32 20480    // padded slice stride (u32)
#define SLICE_U128 (SLICE_U32 / 4)   // 5120 uint4 = 5 * NT exactly
#define OWN_U128  625      // NPB/4 uint4 per sub-block
#define PAIRS  32          // edge-pair slots per node (CAP/2)
#define CTR_STRIDE 32      // 128 B between per-slice counters

typedef unsigned int uint;
typedef unsigned long long ull;
typedef _Float16 h2_t __attribute__((ext_vector_type(2)));
typedef uint u32x4 __attribute__((ext_vector_type(4)));

// MALL-coherent accessors — RELAXED ONLY, one uniform protocol everywhere.
// (acquire/release = whole-L2 inv/wb on gfx950: rounds 8/10 disease. Runtime
// protocol selection: round-13 hang. Neither ever again.)
#define AT_LDI(p)    __hip_atomic_load((const int*)(p), __ATOMIC_RELAXED, __HIP_MEMORY_SCOPE_AGENT)
#define AT_ADDI(p,v) __hip_atomic_fetch_add((int*)(p), (v), __ATOMIC_RELAXED, __HIP_MEMORY_SCOPE_AGENT)

// 16-B MALL-coherent accesses: same sc0 sc1 (L1+L2 bypass) policy the
// compiler emits for agent-scope relaxed atomics, at dwordx4 width.
__device__ __forceinline__ void st128_mall(u32x4* p, u32x4 v) {
    asm volatile("global_store_dwordx4 %0, %1, off sc0 sc1"
                 :: "v"(p), "v"(v) : "memory");
}

__device__ __forceinline__ float fdot2u(uint w, uint h, float acc) {
    union { uint u; h2_t h; } a, b; a.u = w; b.u = h;
    return __builtin_amdgcn_fdot2(a.h, b.h, acc, false);
}

// ---------------------------------------------------------------------------
// setup: zero both h buffers (incl. padding), cnt, meta, counters
// ---------------------------------------------------------------------------
__global__ void setup_kernel(uint* __restrict__ hGA, uint* __restrict__ hGB,
                             int* __restrict__ cnt,
                             uint* __restrict__ colpair, uint* __restrict__ wpair,
                             int* __restrict__ mctr) {
    int idx = blockIdx.x * blockDim.x + threadIdx.x;
    int stride = gridDim.x * blockDim.x;
    for (int i = idx; i < NSLICE * SLICE_U32; i += stride) { hGA[i] = 0u; hGB[i] = 0u; }
    for (int i = idx; i < N_NODES; i += stride) cnt[i] = 0;
    for (int i = idx; i < PAIRS * N_NODES; i += stride) { colpair[i] = 0u; wpair[i] = 0u; }
    for (int i = idx; i < NSLICE * CTR_STRIDE; i += stride) mctr[i] = 0;
}

// ---------------------------------------------------------------------------
// input scatter: bin[in_idx[i]][b] = bias + in_w[i]*x[b][i], last-wins.
// Flags the node (bit 30 of cnt).
// ---------------------------------------------------------------------------
__global__ void input_scatter_kernel(float* __restrict__ bin,
                                     const float* __restrict__ x,
                                     const float* __restrict__ in_w,
                                     const int* __restrict__ in_idx,
                                     const float* __restrict__ biases,
                                     int* __restrict__ cnt) {
    int i = blockIdx.x;
    int b = threadIdx.x;
    int node = in_idx[i];
    if (b == 0) atomicOr(&cnt[node], FLAG_BIT);
    for (int j = i + 1; j < N_IN; j++)
        if (in_idx[j] == node) return;
    bin[node * BATCH + b] = biases[node] + in_w[i] * x[b * N_IN + i];
}

// ---------------------------------------------------------------------------
// COO -> paired transposed ELL in NODE space (atomicOr into 16-bit subwords)
// ---------------------------------------------------------------------------
__global__ void ell_build_kernel(const int* __restrict__ rows,
                                 const int* __restrict__ cols,
                                 const float* __restrict__ rec_w,
                                 uint* __restrict__ colpair, uint* __restrict__ wpair,
                                 int* __restrict__ cnt) {
    int e = blockIdx.x * blockDim.x + threadIdx.x;
    if (e >= N_EDGES) return;
    int r = rows[e];
    int s = atomicAdd(&cnt[r], 1) & CNT_MASK;
    if (s < CAP) {
        int p = s >> 1, sh = (s & 1) * 16;
        atomicOr(&colpair[(size_t)p * N_NODES + r], (uint)cols[e] << sh);
        uint hw = (uint)__half_as_ushort(__float2half(rec_w[e]));
        atomicOr(&wpair[(size_t)p * N_NODES + r], hw << sh);
    }
}

// ---------------------------------------------------------------------------
// per-chunk descending counting sort by degree.
// permG[rank] = node, rankOf[node] = rank (chunk-local ranges preserved).
// ---------------------------------------------------------------------------
__global__ __launch_bounds__(NT) void sort_kernel(const int* __restrict__ cnt,
                                                  int* __restrict__ permG,
                                                  int* __restrict__ rankOf) {
    __shared__ int hist[65], off[65];
    int nbase = blockIdx.x * NPB;
    int tid = threadIdx.x;
    if (tid < 65) hist[tid] = 0;
    __syncthreads();
    for (int r = tid; r < NPB; r += NT) {
        int c = cnt[nbase + r] & CNT_MASK; if (c > CAP) c = CAP;
        atomicAdd(&hist[c], 1);
    }
    __syncthreads();
    if (tid == 0) {
        int run = 0;
        for (int c = CAP; c >= 0; c--) { off[c] = run; run += hist[c]; }
    }
    __syncthreads();
    for (int r = tid; r < NPB; r += NT) {
        int c = cnt[nbase + r] & CNT_MASK; if (c > CAP) c = CAP;
        int rk = atomicAdd(&off[c], 1);
        permG[nbase + rk] = nbase + r;
        rankOf[nbase + r] = nbase + rk;
    }
}

// reorder meta into RANK space, remap columns into RANK space, and merge
// {colpack, wpack} into one uint2 (single dwordx2 load in the hot loop)
__global__ void reorder_kernel(const uint* __restrict__ colpair,
                               const uint* __restrict__ wpair,
                               const int* __restrict__ permG,
                               const int* __restrict__ rankOf,
                               uint2* __restrict__ cwR) {
    int r = blockIdx.x * blockDim.x + threadIdx.x;
    int p = blockIdx.y;
    if (r >= N_NODES) return;
    size_t o = (size_t)p * N_NODES;
    int n = permG[r];
    uint cc = colpair[o + n];
    uint lo = (uint)rankOf[cc & 0xFFFFu];
    uint hi = (uint)rankOf[cc >> 16];
    cwR[o + r] = make_uint2(lo | (hi << 16), wpair[o + n]);
}

// ---------------------------------------------------------------------------
// shared pieces
// ---------------------------------------------------------------------------
__device__ __forceinline__ uint finish_node(float a0, float a1, float b0, float b1) {
    float r0 = b0 + a0, r1 = b1 + a1;
    float u0 = (r0 < 0.f) ? r0 * LEAK : r0;
    float u1 = (r1 < 0.f) ? r1 * LEAK : r1;
    float v0 = (u0 > 0.5f) ? (1.0f - 0.25f / u0) : u0;
    float v1 = (u1 > 0.5f) ? (1.0f - 0.25f / u1) : u1;
    union { __half2 h; uint u; } p;
    p.h = __halves2half2(__float2half(v0), __float2half(v1));
    return p.u;
}

// thread owns 3 ADJACENT ranks (3*tid..3*tid+2): sorted -> near-uniform trip.
__device__ __forceinline__ void hoist_consts(
        int nbase, int tid, int s,
        const int* __restrict__ cnt, const int* __restrict__ permG,
        const float* __restrict__ bin, const float* __restrict__ biases,
        int* rank, float* mb0, float* mb1, bool* ma, int& kp) {
    int kmax = 0;
#pragma unroll
    for (int j = 0; j < 3; j++) {
        int sl = 3 * tid + j;
        ma[j] = (sl < NPB);
        rank[j] = nbase + (ma[j] ? sl : 0);
        int n = permG[rank[j]];
        int cv = cnt[n];
        int c = cv & CNT_MASK; if (c > CAP) c = CAP;
        if (ma[j] && c > kmax) kmax = c;
        if (cv & FLAG_BIT) {
            mb0[j] = bin[(size_t)n * BATCH + 2 * s];
            mb1[j] = bin[(size_t)n * BATCH + 2 * s + 1];
        } else {
            float bb = biases[n]; mb0[j] = bb; mb1[j] = bb;
        }
    }
    kp = (kmax + 1) >> 1;
}

// 3 rank streams x paired edges: 6 independent ds_reads/iter, fdot2 accum.
__device__ __forceinline__ void compute_pairs(
        const int* rank, int kp,
        const uint2* __restrict__ cwR,
        const uint* __restrict__ lds_h, float* a0, float* a1) {
    a0[0] = a0[1] = a0[2] = 0.f;
    a1[0] = a1[1] = a1[2] = 0.f;
#pragma unroll 2
    for (int p = 0; p < kp; p++) {
        size_t o = (size_t)p * N_NODES;
#pragma unroll
        for (int j = 0; j < 3; j++) {
            uint2 m = cwR[o + rank[j]];
            uint ha = lds_h[m.x & 0xFFFFu];
            uint hb = lds_h[m.x >> 16];
            uint lo = __builtin_amdgcn_perm(hb, ha, 0x05040100u);
            uint hi = __builtin_amdgcn_perm(hb, ha, 0x07060302u);
            a0[j] = fdot2u(m.y, lo, a0[j]);
            a1[j] = fdot2u(m.y, hi, a1[j]);
        }
    }
}

// ---------------------------------------------------------------------------
// persistent kernel: proven MALL skeleton, exchange widened to 16 B sc0 sc1
// accesses (same coherence point as agent atomics, 2x fewer transactions,
// 5-deep load batches). Barrier: one relaxed MALL counter per slice.
// ---------------------------------------------------------------------------
__global__ __launch_bounds__(NT) void persistent_kernel(
        uint* hGA, uint* hGB,
        const float* __restrict__ bin, const float* __restrict__ biases,
        const uint2* __restrict__ cwR,
        const int* __restrict__ cnt, const int* __restrict__ permG,
        int* mctr) {
    extern __shared__ uint lds_h[];          // SLICE_U32 u32 = 80 KB mirror
    int bid = blockIdx.x, tid = threadIdx.x;
    int s = bid >> 3, sub = bid & 7;         // sub == bid%8 == XCD (meta-local)
    int nbase = sub * NPB;

    int rank[3]; float mb0[3], mb1[3]; bool ma[3]; int kp;
    hoist_consts(nbase, tid, s, cnt, permG, bin, biases, rank, mb0, mb1, ma, kp);

    for (int i = tid; i < SLICE_U32; i += NT) lds_h[i] = 0u;   // h_{-1} = 0
    __syncthreads();

    uint* hA_s = hGA + (size_t)s * SLICE_U32;
    uint* hB_s = hGB + (size_t)s * SLICE_U32;
    int* mc = &mctr[s * CTR_STRIDE];

    for (int t = 0; t < ITERS; t++) {
        uint* hout = (t & 1) ? hB_s : hA_s;

        float a0[3], a1[3];
        compute_pairs(rank, kp, cwR, lds_h, a0, a1);
        uint v[3];
#pragma unroll
        for (int j = 0; j < 3; j++) v[j] = finish_node(a0[j], a1[j], mb0[j], mb1[j]);

        __syncthreads();                     // all LDS reads of step t done
#pragma unroll
        for (int j = 0; j < 3; j++)
            if (ma[j]) lds_h[rank[j]] = v[j];
        __syncthreads();                     // own LDS range fresh

        // publish own range: 625 coalesced 16B MALL stores (staged via LDS)
        if (tid < OWN_U128) {
            int i = sub * OWN_U128 + tid;
            st128_mall((u32x4*)hout + i, ((const u32x4*)lds_h)[i]);
        }
        if (t == ITERS - 1) break;

        __syncthreads();                     // publish drained (vmcnt0 @ barrier)
        if (tid == 0) {
            AT_ADDI(mc, 1);
            int target = BPS * (t + 1);
            while (AT_LDI(mc) < target) __builtin_amdgcn_s_sleep(2);
        }
        __syncthreads();

        // refresh the whole slice: 5x batched 16B MALL loads per thread
        // (own range reloaded with identical values - branch-free, deep MLP)
        {
            const u32x4* src = (const u32x4*)hout;
            u32x4* dst = (u32x4*)lds_h;
            int i0 = tid, i1 = tid + NT, i2 = tid + 2 * NT,
                i3 = tid + 3 * NT, i4 = tid + 4 * NT;
            u32x4 v0, v1, v2, v3, v4;
            asm volatile(
                "global_load_dwordx4 %0, %5, off sc0 sc1\n\t"
                "global_load_dwordx4 %1, %6, off sc0 sc1\n\t"
                "global_load_dwordx4 %2, %7, off sc0 sc1\n\t"
                "global_load_dwordx4 %3, %8, off sc0 sc1\n\t"
                "global_load_dwordx4 %4, %9, off sc0 sc1\n\t"
                "s_waitcnt vmcnt(0)"
                : "=&v"(v0), "=&v"(v1), "=&v"(v2), "=&v"(v3), "=&v"(v4)
                : "v"(src + i0), "v"(src + i1), "v"(src + i2),
                  "v"(src + i3), "v"(src + i4)
                : "memory");
            dst[i0] = v0; dst[i1] = v1; dst[i2] = v2; dst[i3] = v3; dst[i4] = v4;
        }
        __syncthreads();
    }
}

// ---------------------------------------------------------------------------
// fallback: one step per launch (dispatch boundary = sync), same numerics
// ---------------------------------------------------------------------------
__global__ __launch_bounds__(NT) void step_kernel(
        const uint* __restrict__ hprev, uint* __restrict__ hnext,
        const float* __restrict__ bin, const float* __restrict__ biases,
        const uint2* __restrict__ cwR,
        const int* __restrict__ cnt, const int* __restrict__ permG) {
    extern __shared__ uint lds_h[];
    int bid = blockIdx.x, tid = threadIdx.x;
    int s = bid >> 3, sub = bid & 7;
    int nbase = sub * NPB;

    int rank[3]; float mb0[3], mb1[3]; bool ma[3]; int kp;
    hoist_consts(nbase, tid, s, cnt, permG, bin, biases, rank, mb0, mb1, ma, kp);

    const uint* hp = hprev + (size_t)s * SLICE_U32;
    for (int i = tid; i < SLICE_U32; i += NT) lds_h[i] = hp[i];
    __syncthreads();

    float a0[3], a1[3];
    compute_pairs(rank, kp, cwR, lds_h, a0, a1);
    uint* ho = hnext + (size_t)s * SLICE_U32;
#pragma unroll
    for (int j = 0; j < 3; j++)
        if (ma[j]) ho[rank[j]] = finish_node(a0[j], a1[j], mb0[j], mb1[j]);
}

// ---------------------------------------------------------------------------
// output gather: out[b][o] = out_w[o] * h[rankOf[out_idx[o]]][b]
// ---------------------------------------------------------------------------
__global__ void output_kernel(const uint* __restrict__ hfinal,
                              const int* __restrict__ out_idx,
                              const int* __restrict__ rankOf,
                              const float* __restrict__ out_w,
                              float* __restrict__ out) {
    int o = threadIdx.x;
    int b = blockIdx.x;
    uint v = hfinal[(size_t)(b >> 1) * SLICE_U32 + rankOf[out_idx[o]]];
    unsigned short h = (b & 1) ? (unsigned short)(v >> 16) : (unsigned short)(v & 0xFFFF);
    out[b * N_OUT + o] = out_w[o] * __half2float(__ushort_as_half(h));
}

// ---------------------------------------------------------------------------
extern "C" void kernel_launch(void* const* d_in, const int* in_sizes, int n_in,
                              void* d_out, int out_size, void* d_ws, size_t ws_size,
                              hipStream_t stream) {
    const float* x      = (const float*)d_in[0];
    const float* in_w   = (const float*)d_in[1];
    const float* out_w  = (const float*)d_in[2];
    const float* rec_w  = (const float*)d_in[3];
    const float* biases = (const float*)d_in[4];
    const int*   rows   = (const int*)d_in[5];
    const int*   cols   = (const int*)d_in[6];
    const int*   in_idx = (const int*)d_in[7];
    const int*   oidx   = (const int*)d_in[8];
    float* out = (float*)d_out;

    char* ws = (char*)d_ws;
    uint*  hGA     = (uint*)ws;  ws += (size_t)NSLICE * SLICE_U32 * 4;  // 2.62 MB
    uint*  hGB     = (uint*)ws;  ws += (size_t)NSLICE * SLICE_U32 * 4;  // 2.62 MB
    float* bin     = (float*)ws; ws += (size_t)N_NODES * BATCH * 4;     // 5.12 MB
    uint*  colpair = (uint*)ws;  ws += (size_t)PAIRS * N_NODES * 4;     // 2.56 MB
    uint*  wpair   = (uint*)ws;  ws += (size_t)PAIRS * N_NODES * 4;     // 2.56 MB
    uint2* cwR     = (uint2*)ws; ws += (size_t)PAIRS * N_NODES * 8;     // 5.12 MB
    int*   cnt     = (int*)ws;   ws += (size_t)N_NODES * 4;             // 80 KB
    int*   permG   = (int*)ws;   ws += (size_t)N_NODES * 4;             // 80 KB
    int*   rankOf  = (int*)ws;   ws += (size_t)N_NODES * 4;             // 80 KB
    int*   mctr    = (int*)ws;   ws += (size_t)NSLICE * CTR_STRIDE * 4;

    const int shmem = SLICE_U32 * 4;   // 81920 B dynamic LDS
    hipFuncSetAttribute((const void*)persistent_kernel,
                        hipFuncAttributeMaxDynamicSharedMemorySize, shmem);
    hipFuncSetAttribute((const void*)step_kernel,
                        hipFuncAttributeMaxDynamicSharedMemorySize, shmem);

    setup_kernel<<<2048, 256, 0, stream>>>(hGA, hGB, cnt, colpair, wpair, mctr);
    input_scatter_kernel<<<N_IN, BATCH, 0, stream>>>(bin, x, in_w, in_idx,
                                                     biases, cnt);
    ell_build_kernel<<<(N_EDGES + 255) / 256, 256, 0, stream>>>(rows, cols, rec_w,
                                                                colpair, wpair, cnt);
    sort_kernel<<<N_NODES / NPB, NT, 0, stream>>>(cnt, permG, rankOf);
    reorder_kernel<<<dim3((N_NODES + 255) / 256, PAIRS), 256, 0, stream>>>(
        colpair, wpair, permG, rankOf, cwR);

    void* args[] = { (void*)&hGA, (void*)&hGB, (void*)&bin, (void*)&biases,
                     (void*)&cwR, (void*)&cnt, (void*)&permG, (void*)&mctr };
    hipError_t ce = hipLaunchCooperativeKernel((void*)persistent_kernel,
                                               dim3(NBLK), dim3(NT),
                                               args, shmem, stream);
    const uint* hfinal;
    if (ce == hipSuccess) {
        hfinal = hGB;                 // t=149 (odd) wrote hGB
    } else {
        uint* pa = hGA;
        uint* pb = hGB;
        for (int t = 0; t < ITERS; t++) {
            step_kernel<<<NBLK, NT, shmem, stream>>>(pa, pb, bin, biases,
                                                     cwR, cnt, permG);
            uint* tmp = pa; pa = pb; pb = tmp;
        }
        hfinal = pa;                  // last write landed in the buffer now in pa
    }

    output_kernel<<<BATCH, N_OUT, 0, stream>>>(hfinal, oidx, rankOf, out_w, out);
}

// Round 17
// 1067.074 us; speedup vs baseline: 1.9150x; 1.0204x over previous
//
#include <hip/hip_runtime.h>
#include <hip/hip_fp16.h>

#define N_NODES 20000
#define N_EDGES 320000
#define BATCH   64
#define N_IN    128
#define N_OUT   256
#define CAP     64
#define ITERS   150
#define LEAK    0.01f

#define CNT_MASK 0x3FFFFFFF
#define FLAG_BIT (1 << 30)

#define NSLICE 32          // batch pairs; slice s owns batch elems {2s,2s+1}
#define BPS    8           // blocks per slice
#define NPB    2500        // ranks per block-chunk
#define NT     1024        // threads per block
#define NBLK   (NSLICE * BPS)
#define SLICE_U32 20480    // padded slice stride (u32)
#define OWN_U128  625      // NPB/4 uint4 per sub-block
#define PAIRS  32          // edge-pair slots per node (CAP/2)
#define TAG_STRIDE 32      // uints -> 128 B between tags

typedef unsigned int uint;
typedef unsigned long long ull;
typedef _Float16 h2_t __attribute__((ext_vector_type(2)));
typedef uint u32x4 __attribute__((ext_vector_type(4)));

// MALL-coherent accessors — RELAXED sc0 sc1 ONLY (L1+L2 bypass; Infinity-
// Cache-coherent). Rounds 9/10/11/14/15 proved this protocol; acquire/release
// (L2 inv/wb) and the XCD-L2 exchange path (hangs, r13/r16) are banned.
__device__ __forceinline__ void st128_mall(u32x4* p, u32x4 v) {
    asm volatile("global_store_dwordx4 %0, %1, off sc0 sc1"
                 :: "v"(p), "v"(v) : "memory");
}
__device__ __forceinline__ void st32_mall(uint* p, uint v) {
    asm volatile("global_store_dword %0, %1, off sc0 sc1"
                 :: "v"(p), "v"(v) : "memory");
}
__device__ __forceinline__ uint ld32_mall(const uint* p) {
    uint v;
    asm volatile("global_load_dword %0, %1, off sc0 sc1\n\t"
                 "s_waitcnt vmcnt(0)"
                 : "=v"(v) : "v"(p) : "memory");
    return v;
}

__device__ __forceinline__ float fdot2u(uint w, uint h, float acc) {
    union { uint u; h2_t h; } a, b; a.u = w; b.u = h;
    return __builtin_amdgcn_fdot2(a.h, b.h, acc, false);
}

// ---------------------------------------------------------------------------
// setup: zero both h buffers (incl. padding), cnt, meta, tags
// ---------------------------------------------------------------------------
__global__ void setup_kernel(uint* __restrict__ hGA, uint* __restrict__ hGB,
                             int* __restrict__ cnt,
                             uint* __restrict__ colpair, uint* __restrict__ wpair,
                             uint* __restrict__ tags) {
    int idx = blockIdx.x * blockDim.x + threadIdx.x;
    int stride = gridDim.x * blockDim.x;
    for (int i = idx; i < NSLICE * SLICE_U32; i += stride) { hGA[i] = 0u; hGB[i] = 0u; }
    for (int i = idx; i < N_NODES; i += stride) cnt[i] = 0;
    for (int i = idx; i < PAIRS * N_NODES; i += stride) { colpair[i] = 0u; wpair[i] = 0u; }
    for (int i = idx; i < NSLICE * BPS * TAG_STRIDE; i += stride) tags[i] = 0u;
}

// ---------------------------------------------------------------------------
// input scatter: bin[in_idx[i]][b] = bias + in_w[i]*x[b][i], last-wins.
// Flags the node (bit 30 of cnt).
// ---------------------------------------------------------------------------
__global__ void input_scatter_kernel(float* __restrict__ bin,
                                     const float* __restrict__ x,
                                     const float* __restrict__ in_w,
                                     const int* __restrict__ in_idx,
                                     const float* __restrict__ biases,
                                     int* __restrict__ cnt) {
    int i = blockIdx.x;
    int b = threadIdx.x;
    int node = in_idx[i];
    if (b == 0) atomicOr(&cnt[node], FLAG_BIT);
    for (int j = i + 1; j < N_IN; j++)
        if (in_idx[j] == node) return;
    bin[node * BATCH + b] = biases[node] + in_w[i] * x[b * N_IN + i];
}

// ---------------------------------------------------------------------------
// COO -> paired transposed ELL in NODE space (atomicOr into 16-bit subwords)
// ---------------------------------------------------------------------------
__global__ void ell_build_kernel(const int* __restrict__ rows,
                                 const int* __restrict__ cols,
                                 const float* __restrict__ rec_w,
                                 uint* __restrict__ colpair, uint* __restrict__ wpair,
                                 int* __restrict__ cnt) {
    int e = blockIdx.x * blockDim.x + threadIdx.x;
    if (e >= N_EDGES) return;
    int r = rows[e];
    int s = atomicAdd(&cnt[r], 1) & CNT_MASK;
    if (s < CAP) {
        int p = s >> 1, sh = (s & 1) * 16;
        atomicOr(&colpair[(size_t)p * N_NODES + r], (uint)cols[e] << sh);
        uint hw = (uint)__half_as_ushort(__float2half(rec_w[e]));
        atomicOr(&wpair[(size_t)p * N_NODES + r], hw << sh);
    }
}

// ---------------------------------------------------------------------------
// per-chunk descending counting sort by degree.
// ---------------------------------------------------------------------------
__global__ __launch_bounds__(NT) void sort_kernel(const int* __restrict__ cnt,
                                                  int* __restrict__ permG,
                                                  int* __restrict__ rankOf) {
    __shared__ int hist[65], off[65];
    int nbase = blockIdx.x * NPB;
    int tid = threadIdx.x;
    if (tid < 65) hist[tid] = 0;
    __syncthreads();
    for (int r = tid; r < NPB; r += NT) {
        int c = cnt[nbase + r] & CNT_MASK; if (c > CAP) c = CAP;
        atomicAdd(&hist[c], 1);
    }
    __syncthreads();
    if (tid == 0) {
        int run = 0;
        for (int c = CAP; c >= 0; c--) { off[c] = run; run += hist[c]; }
    }
    __syncthreads();
    for (int r = tid; r < NPB; r += NT) {
        int c = cnt[nbase + r] & CNT_MASK; if (c > CAP) c = CAP;
        int rk = atomicAdd(&off[c], 1);
        permG[nbase + rk] = nbase + r;
        rankOf[nbase + r] = nbase + rk;
    }
}

// reorder meta into RANK space, remap columns, merge into one uint2
__global__ void reorder_kernel(const uint* __restrict__ colpair,
                               const uint* __restrict__ wpair,
                               const int* __restrict__ permG,
                               const int* __restrict__ rankOf,
                               uint2* __restrict__ cwR) {
    int r = blockIdx.x * blockDim.x + threadIdx.x;
    int p = blockIdx.y;
    if (r >= N_NODES) return;
    size_t o = (size_t)p * N_NODES;
    int n = permG[r];
    uint cc = colpair[o + n];
    uint lo = (uint)rankOf[cc & 0xFFFFu];
    uint hi = (uint)rankOf[cc >> 16];
    cwR[o + r] = make_uint2(lo | (hi << 16), wpair[o + n]);
}

// ---------------------------------------------------------------------------
// shared pieces
// ---------------------------------------------------------------------------
__device__ __forceinline__ uint finish_node(float a0, float a1, float b0, float b1) {
    float r0 = b0 + a0, r1 = b1 + a1;
    float u0 = (r0 < 0.f) ? r0 * LEAK : r0;
    float u1 = (r1 < 0.f) ? r1 * LEAK : r1;
    float v0 = (u0 > 0.5f) ? (1.0f - 0.25f / u0) : u0;
    float v1 = (u1 > 0.5f) ? (1.0f - 0.25f / u1) : u1;
    union { __half2 h; uint u; } p;
    p.h = __halves2half2(__float2half(v0), __float2half(v1));
    return p.u;
}

__device__ __forceinline__ void hoist_consts(
        int nbase, int tid, int s,
        const int* __restrict__ cnt, const int* __restrict__ permG,
        const float* __restrict__ bin, const float* __restrict__ biases,
        int* rank, float* mb0, float* mb1, bool* ma, int& kp) {
    int kmax = 0;
#pragma unroll
    for (int j = 0; j < 3; j++) {
        int sl = 3 * tid + j;
        ma[j] = (sl < NPB);
        rank[j] = nbase + (ma[j] ? sl : 0);
        int n = permG[rank[j]];
        int cv = cnt[n];
        int c = cv & CNT_MASK; if (c > CAP) c = CAP;
        if (ma[j] && c > kmax) kmax = c;
        if (cv & FLAG_BIT) {
            mb0[j] = bin[(size_t)n * BATCH + 2 * s];
            mb1[j] = bin[(size_t)n * BATCH + 2 * s + 1];
        } else {
            float bb = biases[n]; mb0[j] = bb; mb1[j] = bb;
        }
    }
    kp = (kmax + 1) >> 1;
}

// 3 rank streams x paired edges: 6 independent ds_reads/iter, fdot2 accum.
__device__ __forceinline__ void compute_pairs(
        const int* rank, int kp,
        const uint2* __restrict__ cwR,
        const uint* __restrict__ lds_h, float* a0, float* a1) {
    a0[0] = a0[1] = a0[2] = 0.f;
    a1[0] = a1[1] = a1[2] = 0.f;
#pragma unroll 2
    for (int p = 0; p < kp; p++) {
        size_t o = (size_t)p * N_NODES;
#pragma unroll
        for (int j = 0; j < 3; j++) {
            uint2 m = cwR[o + rank[j]];
            uint ha = lds_h[m.x & 0xFFFFu];
            uint hb = lds_h[m.x >> 16];
            uint lo = __builtin_amdgcn_perm(hb, ha, 0x05040100u);
            uint hi = __builtin_amdgcn_perm(hb, ha, 0x07060302u);
            a0[j] = fdot2u(m.y, lo, a0[j]);
            a1[j] = fdot2u(m.y, hi, a1[j]);
        }
    }
}

// ---------------------------------------------------------------------------
// persistent kernel: round-15 MALL skeleton with a TAG barrier.
// After publish drains (__syncthreads vmcnt-drain), tid0 writes tag[s][sub]
// = t+1 (monotone, single-writer, MALL). Refresh waves poll only the tag of
// the sub-range they load (lane-0 poll), then load it; own sub-range is
// skipped (already fresh in LDS). Same progress invariant as the proven
// counter barrier; no central atomic, no protocol selection.
// ---------------------------------------------------------------------------
__global__ __launch_bounds__(NT) void persistent_kernel(
        uint* hGA, uint* hGB,
        const float* __restrict__ bin, const float* __restrict__ biases,
        const uint2* __restrict__ cwR,
        const int* __restrict__ cnt, const int* __restrict__ permG,
        uint* tags) {
    extern __shared__ uint lds_h[];          // SLICE_U32 u32 = 80 KB mirror
    int bid = blockIdx.x, tid = threadIdx.x;
    int s = bid >> 3, sub = bid & 7;
    int nbase = sub * NPB;
    const int wave = tid >> 6, lane = tid & 63;
    const int sb = wave >> 1, half = wave & 1;   // refresh assignment

    int rank[3]; float mb0[3], mb1[3]; bool ma[3]; int kp;
    hoist_consts(nbase, tid, s, cnt, permG, bin, biases, rank, mb0, mb1, ma, kp);

    for (int i = tid; i < SLICE_U32; i += NT) lds_h[i] = 0u;   // h_{-1} = 0
    __syncthreads();

    uint* hA_s = hGA + (size_t)s * SLICE_U32;
    uint* hB_s = hGB + (size_t)s * SLICE_U32;
    uint* mytag = &tags[(s * BPS + sub) * TAG_STRIDE];

    for (int t = 0; t < ITERS; t++) {
        uint* hout = (t & 1) ? hB_s : hA_s;

        float a0[3], a1[3];
        compute_pairs(rank, kp, cwR, lds_h, a0, a1);
        uint v[3];
#pragma unroll
        for (int j = 0; j < 3; j++) v[j] = finish_node(a0[j], a1[j], mb0[j], mb1[j]);

        __syncthreads();                     // all LDS reads of step t done
#pragma unroll
        for (int j = 0; j < 3; j++)
            if (ma[j]) lds_h[rank[j]] = v[j];
        __syncthreads();                     // own LDS range fresh

        // publish own range: 625 coalesced 16B MALL stores (staged via LDS)
        if (tid < OWN_U128) {
            int i = sub * OWN_U128 + tid;
            st128_mall((u32x4*)hout + i, ((const u32x4*)lds_h)[i]);
        }
        if (t == ITERS - 1) break;

        __syncthreads();                     // publish drained (vmcnt0 @ barrier)
        if (tid == 0) st32_mall(mytag, (uint)(t + 1));

        // refresh remote sub-ranges: poll that sub-block's tag, then load.
        if (sb != sub) {
            if (lane == 0) {
                const uint* rt = &tags[(s * BPS + sb) * TAG_STRIDE];
                while (ld32_mall(rt) < (uint)(t + 1)) __builtin_amdgcn_s_sleep(2);
            }
            // wave reconverged: 2 waves cover this sub-range's 625 uint4
            const u32x4* sp = (const u32x4*)hout + sb * OWN_U128;
            u32x4* dp = (u32x4*)lds_h + sb * OWN_U128;
            int it0 = half * 64 + lane;          // 0..127
            int it4 = it0 + 512;                 // 512..639 (guard > 624)
            int c4 = (it4 <= 624) ? it4 : 624;
            u32x4 r0, r1, r2, r3, r4;
            asm volatile(
                "global_load_dwordx4 %0, %5, off sc0 sc1\n\t"
                "global_load_dwordx4 %1, %6, off sc0 sc1\n\t"
                "global_load_dwordx4 %2, %7, off sc0 sc1\n\t"
                "global_load_dwordx4 %3, %8, off sc0 sc1\n\t"
                "global_load_dwordx4 %4, %9, off sc0 sc1\n\t"
                "s_waitcnt vmcnt(0)"
                : "=&v"(r0), "=&v"(r1), "=&v"(r2), "=&v"(r3), "=&v"(r4)
                : "v"(sp + it0), "v"(sp + it0 + 128), "v"(sp + it0 + 256),
                  "v"(sp + it0 + 384), "v"(sp + c4)
                : "memory");
            dp[it0] = r0; dp[it0 + 128] = r1; dp[it0 + 256] = r2;
            dp[it0 + 384] = r3;
            if (it4 <= 624) dp[it4] = r4;
        }
        __syncthreads();                     // all refresh done before compute
    }
}

// ---------------------------------------------------------------------------
// fallback: one step per launch (dispatch boundary = sync), same numerics
// ---------------------------------------------------------------------------
__global__ __launch_bounds__(NT) void step_kernel(
        const uint* __restrict__ hprev, uint* __restrict__ hnext,
        const float* __restrict__ bin, const float* __restrict__ biases,
        const uint2* __restrict__ cwR,
        const int* __restrict__ cnt, const int* __restrict__ permG) {
    extern __shared__ uint lds_h[];
    int bid = blockIdx.x, tid = threadIdx.x;
    int s = bid >> 3, sub = bid & 7;
    int nbase = sub * NPB;

    int rank[3]; float mb0[3], mb1[3]; bool ma[3]; int kp;
    hoist_consts(nbase, tid, s, cnt, permG, bin, biases, rank, mb0, mb1, ma, kp);

    const uint* hp = hprev + (size_t)s * SLICE_U32;
    for (int i = tid; i < SLICE_U32; i += NT) lds_h[i] = hp[i];
    __syncthreads();

    float a0[3], a1[3];
    compute_pairs(rank, kp, cwR, lds_h, a0, a1);
    uint* ho = hnext + (size_t)s * SLICE_U32;
#pragma unroll
    for (int j = 0; j < 3; j++)
        if (ma[j]) ho[rank[j]] = finish_node(a0[j], a1[j], mb0[j], mb1[j]);
}

// ---------------------------------------------------------------------------
// output gather: out[b][o] = out_w[o] * h[rankOf[out_idx[o]]][b]
// ---------------------------------------------------------------------------
__global__ void output_kernel(const uint* __restrict__ hfinal,
                              const int* __restrict__ out_idx,
                              const int* __restrict__ rankOf,
                              const float* __restrict__ out_w,
                              float* __restrict__ out) {
    int o = threadIdx.x;
    int b = blockIdx.x;
    uint v = hfinal[(size_t)(b >> 1) * SLICE_U32 + rankOf[out_idx[o]]];
    unsigned short h = (b & 1) ? (unsigned short)(v >> 16) : (unsigned short)(v & 0xFFFF);
    out[b * N_OUT + o] = out_w[o] * __half2float(__ushort_as_half(h));
}

// ---------------------------------------------------------------------------
extern "C" void kernel_launch(void* const* d_in, const int* in_sizes, int n_in,
                              void* d_out, int out_size, void* d_ws, size_t ws_size,
                              hipStream_t stream) {
    const float* x      = (const float*)d_in[0];
    const float* in_w   = (const float*)d_in[1];
    const float* out_w  = (const float*)d_in[2];
    const float* rec_w  = (const float*)d_in[3];
    const float* biases = (const float*)d_in[4];
    const int*   rows   = (const int*)d_in[5];
    const int*   cols   = (const int*)d_in[6];
    const int*   in_idx = (const int*)d_in[7];
    const int*   oidx   = (const int*)d_in[8];
    float* out = (float*)d_out;

    char* ws = (char*)d_ws;
    uint*  hGA     = (uint*)ws;  ws += (size_t)NSLICE * SLICE_U32 * 4;  // 2.62 MB
    uint*  hGB     = (uint*)ws;  ws += (size_t)NSLICE * SLICE_U32 * 4;  // 2.62 MB
    float* bin     = (float*)ws; ws += (size_t)N_NODES * BATCH * 4;     // 5.12 MB
    uint*  colpair = (uint*)ws;  ws += (size_t)PAIRS * N_NODES * 4;     // 2.56 MB
    uint*  wpair   = (uint*)ws;  ws += (size_t)PAIRS * N_NODES * 4;     // 2.56 MB
    uint2* cwR     = (uint2*)ws; ws += (size_t)PAIRS * N_NODES * 8;     // 5.12 MB
    int*   cnt     = (int*)ws;   ws += (size_t)N_NODES * 4;             // 80 KB
    int*   permG   = (int*)ws;   ws += (size_t)N_NODES * 4;             // 80 KB
    int*   rankOf  = (int*)ws;   ws += (size_t)N_NODES * 4;             // 80 KB
    uint*  tags    = (uint*)ws;  ws += (size_t)NSLICE * BPS * TAG_STRIDE * 4;

    const int shmem = SLICE_U32 * 4;   // 81920 B dynamic LDS
    hipFuncSetAttribute((const void*)persistent_kernel,
                        hipFuncAttributeMaxDynamicSharedMemorySize, shmem);
    hipFuncSetAttribute((const void*)step_kernel,
                        hipFuncAttributeMaxDynamicSharedMemorySize, shmem);

    setup_kernel<<<2048, 256, 0, stream>>>(hGA, hGB, cnt, colpair, wpair, tags);
    input_scatter_kernel<<<N_IN, BATCH, 0, stream>>>(bin, x, in_w, in_idx,
                                                     biases, cnt);
    ell_build_kernel<<<(N_EDGES + 255) / 256, 256, 0, stream>>>(rows, cols, rec_w,
                                                                colpair, wpair, cnt);
    sort_kernel<<<N_NODES / NPB, NT, 0, stream>>>(cnt, permG, rankOf);
    reorder_kernel<<<dim3((N_NODES + 255) / 256, PAIRS), 256, 0, stream>>>(
        colpair, wpair, permG, rankOf, cwR);

    void* args[] = { (void*)&hGA, (void*)&hGB, (void*)&bin, (void*)&biases,
                     (void*)&cwR, (void*)&cnt, (void*)&permG, (void*)&tags };
    hipError_t ce = hipLaunchCooperativeKernel((void*)persistent_kernel,
                                               dim3(NBLK), dim3(NT),
                                               args, shmem, stream);
    const uint* hfinal;
    if (ce == hipSuccess) {
        hfinal = hGB;                 // t=149 (odd) wrote hGB
    } else {
        uint* pa = hGA;
        uint* pb = hGB;
        for (int t = 0; t < ITERS; t++) {
            step_kernel<<<NBLK, NT, shmem, stream>>>(pa, pb, bin, biases,
                                                     cwR, cnt, permG);
            uint* tmp = pa; pa = pb; pb = tmp;
        }
        hfinal = pa;                  // last write landed in the buffer now in pa
    }

    output_kernel<<<BATCH, N_OUT, 0, stream>>>(hfinal, oidx, rankOf, out_w, out);
}